// Round 11
// baseline (198.191 us; speedup 1.0000x reference)
//
#include <hip/hip_runtime.h>
#include <hip/hip_fp16.h>
#include <stdint.h>

// MaskCrossAttention: B=4, LQ=LKV=1024, C=EMBED=768, NH=12, HD=64, SCALE=0.125
// Round 10: BARRIER-FREE attn. Each wave owns private 3-deep LDS K/V buffers
// (KVBLK=16) and runs stage->vmcnt->compute with NO s_barrier anywhere in the
// kv loop: 12 fully independent wave-pipelines per CU (every prior round kept
// the block's waves in lockstep barriers -- the one untested invariant).
// Launches: prep -> gemm_qkv -> attn -> gemm_out.

typedef _Float16 f16;
typedef __attribute__((ext_vector_type(8))) _Float16 f16x8;
typedef __attribute__((ext_vector_type(4))) _Float16 f16x4;
typedef __attribute__((ext_vector_type(4))) float f32x4;

__device__ __forceinline__ void gload16(const void* g, void* l) {
  __builtin_amdgcn_global_load_lds(
      (__attribute__((address_space(1))) void*)(uintptr_t)g,
      (__attribute__((address_space(3))) void*)(uint32_t)(uintptr_t)l,
      16, 0, 0);
}

// ---------------- fused prep: cvt Xq, cvt Xkv, transpose Wq/Wkv/Wp ----------
__device__ __forceinline__ void cvt4_job(const float* __restrict__ in,
                                         f16* __restrict__ out, int i) {
  float4 v = reinterpret_cast<const float4*>(in)[i];
  f16x4 o = {(f16)v.x, (f16)v.y, (f16)v.z, (f16)v.w};
  reinterpret_cast<f16x4*>(out)[i] = o;
}
__device__ __forceinline__ void transw_job(const float* __restrict__ W,
                                           f16* __restrict__ Wt, int N, int bid,
                                           int tid) {
  int kcb = bid % 96;  // 96 = 768/8
  int n = (bid / 96) * 256 + tid;
  int k0 = kcb * 8;
  f16x8 o;
#pragma unroll
  for (int j = 0; j < 8; ++j) o[j] = (f16)W[(size_t)(k0 + j) * N + n];
  *reinterpret_cast<f16x8*>(Wt + (size_t)n * 768 + k0) = o;
}
__global__ __launch_bounds__(256) void prep_kernel(
    const float* __restrict__ Xq, const float* __restrict__ Xkv,
    const float* __restrict__ Wq, const float* __restrict__ Wkv,
    const float* __restrict__ Wp, f16* __restrict__ Xq_h,
    f16* __restrict__ Xkv_h, f16* __restrict__ WqT, f16* __restrict__ WkvT,
    f16* __restrict__ WpT) {
  const int bid = blockIdx.x, tid = threadIdx.x;
  if (bid < 3072) cvt4_job(Xq, Xq_h, bid * 256 + tid);
  else if (bid < 6144) cvt4_job(Xkv, Xkv_h, (bid - 3072) * 256 + tid);
  else if (bid < 6432) transw_job(Wq, WqT, 768, bid - 6144, tid);
  else if (bid < 7008) transw_job(Wkv, WkvT, 1536, bid - 6432, tid);
  else transw_job(Wp, WpT, 768, bid - 7008, tid);
}

// ---------------- GEMM body: C = A(4096x768) * Bt(N x 768)^T + bias ---------
template <int NDIM, int EPI>
__device__ __forceinline__ void gemm_body(int bid, f16* As, f16* Bs,
                                          const f16* __restrict__ A,
                                          const f16* __restrict__ Bt,
                                          const float* __restrict__ bias,
                                          void* __restrict__ out0,
                                          void* __restrict__ out1) {
  constexpr int KD = 768;
  const int t = threadIdx.x;
  const int lane = t & 63, wid = t >> 6;
  const int bm = bid / (NDIM / 128), bn = bid % (NDIM / 128);
  const int m0 = bm * 128, n0 = bn * 128;
  const int wm = wid >> 1, wn = wid & 1;
  const int cr = lane & 15, grp = lane >> 4;
  f32x4 acc[4][4] = {};
  for (int k0 = 0; k0 < KD; k0 += 32) {
    __syncthreads();
#pragma unroll
    for (int it = 0; it < 2; ++it) {
      int ia = it * 256 + wid * 64 + lane;
      int kc = ia >> 7, row = ia & 127;
      gload16(A + (size_t)(m0 + row) * KD + k0 + kc * 8,
              As + (it * 256 + wid * 64) * 8);
      gload16(Bt + (size_t)(n0 + row) * KD + k0 + kc * 8,
              Bs + (it * 256 + wid * 64) * 8);
    }
    __syncthreads();
    f16x8 af[4], bf[4];
#pragma unroll
    for (int mf = 0; mf < 4; ++mf)
      af[mf] = *reinterpret_cast<const f16x8*>(As + (grp * 128 + wm * 64 + mf * 16 + cr) * 8);
#pragma unroll
    for (int nf = 0; nf < 4; ++nf)
      bf[nf] = *reinterpret_cast<const f16x8*>(Bs + (grp * 128 + wn * 64 + nf * 16 + cr) * 8);
#pragma unroll
    for (int mf = 0; mf < 4; ++mf)
#pragma unroll
      for (int nf = 0; nf < 4; ++nf)
        acc[mf][nf] = __builtin_amdgcn_mfma_f32_16x16x32_f16(af[mf], bf[nf], acc[mf][nf], 0, 0, 0);
  }
#pragma unroll
  for (int mf = 0; mf < 4; ++mf) {
    int m = m0 + wm * 64 + mf * 16 + grp * 4;  // +r per reg
    int b = m >> 10, lrow = m & 1023;
#pragma unroll
    for (int nf = 0; nf < 4; ++nf) {
      int n = n0 + wn * 64 + nf * 16 + cr;
      float bv = bias[n];
      f32x4 v = acc[mf][nf];
      if constexpr (EPI == 0) {
        int h = n >> 6, d = n & 63;
        f16* dst = (f16*)out0 + (((size_t)b * 12 + h) * 1024 + lrow) * 64 + d;
#pragma unroll
        for (int r = 0; r < 4; ++r) dst[(size_t)r * 64] = (f16)((v[r] + bv) * 0.125f);
      } else if constexpr (EPI == 1) {
        if (n < 768) {
          int h = n >> 6, d = n & 63;
          f16* dst = (f16*)out0 + (((size_t)b * 12 + h) * 1024 + lrow) * 64 + d;
#pragma unroll
          for (int r = 0; r < 4; ++r) dst[(size_t)r * 64] = (f16)(v[r] + bv);
        } else {
          int n2 = n - 768;
          int h = n2 >> 6, d = n2 & 63;
          f16x4 o;
#pragma unroll
          for (int r = 0; r < 4; ++r) o[r] = (f16)(v[r] + bv);
          *reinterpret_cast<f16x4*>((f16*)out1 + (((size_t)b * 12 + h) * 64 + d) * 1024 + lrow) = o;
        }
      } else {
        float* dst = (float*)out0 + (size_t)m * 768 + n;
#pragma unroll
        for (int r = 0; r < 4; ++r) dst[(size_t)r * 768] = v[r] + bv;
      }
    }
  }
}

__global__ __launch_bounds__(256) void gemm_qkv_kernel(
    const f16* __restrict__ Xq_h, const f16* __restrict__ WqT,
    const float* __restrict__ bq, f16* __restrict__ Qb,
    const f16* __restrict__ Xkv_h, const f16* __restrict__ WkvT,
    const float* __restrict__ bkv, f16* __restrict__ Kb, f16* __restrict__ VTb) {
  __shared__ f16 As[4096];
  __shared__ f16 Bs[4096];
  const int swz = (blockIdx.x % 8) * 72 + blockIdx.x / 8;  // 576 = 8*72
  if (swz < 192)
    gemm_body<768, 0>(swz, As, Bs, Xq_h, WqT, bq, Qb, nullptr);
  else
    gemm_body<1536, 1>(swz - 192, As, Bs, Xkv_h, WkvT, bkv, Kb, VTb);
}

__global__ __launch_bounds__(256) void gemm_out_kernel(
    const f16* __restrict__ attO, const f16* __restrict__ WpT,
    const float* __restrict__ bp, float* __restrict__ out) {
  __shared__ f16 As[4096];
  __shared__ f16 Bs[4096];
  const int swz = (blockIdx.x % 8) * 24 + blockIdx.x / 8;  // 192 = 8*24
  gemm_body<768, 2>(swz, As, Bs, attO, WpT, bp, out, nullptr);
}

// ---------------- fused flash attention: barrier-free wave pipelines -------
// 768 blocks x 256 threads; wave w owns 16 q-rows AND private LDS (3 x
// (K 2KB + V 2KB)).  64 windows of KVBLK=16.  Per window: stage(t+2) ->
// s_waitcnt vmcnt(9) (tile t + pos t complete; 9 younger ops in flight) ->
// QK^T -> loadpos(t+2) -> softmax -> PV.  NO s_barrier in the loop.
// Block remap: 4 batches of one (h,qtile) adjacent on one XCD (pos L2-shared).
__global__ __launch_bounds__(256, 3) void attn_kernel(
    const f16* __restrict__ Q, const f16* __restrict__ K,
    const f16* __restrict__ VT, const float* __restrict__ pos,
    const float* __restrict__ mask, f16* __restrict__ attO) {
  __shared__ f16 KS[4][3][1024];  // [wave][buf][dc8][kv16][8]
  __shared__ f16 VS[4][3][1024];  // [wave][buf][kc2][d64][8]
  const int t = threadIdx.x;
  const int lane = t & 63, wid = t >> 6;
  const int xcd = blockIdx.x & 7;
  const int j = blockIdx.x >> 3;            // 0..95
  const int gidx = xcd * 24 + (j >> 2);     // 0..191 = h*16 + qtile
  const int b = j & 3;
  const int h = gidx >> 4;
  const int qt = gidx & 15;
  const int bh = b * 12 + h;
  const int cq = lane & 15, grp = lane >> 4;
  const int q = qt * 64 + wid * 16 + cq;
  const f16* Qp = Q + ((size_t)bh * 1024 + q) * 64 + grp * 8;
  const f16x8 qf0 = *reinterpret_cast<const f16x8*>(Qp);
  const f16x8 qf1 = *reinterpret_cast<const f16x8*>(Qp + 32);
  const f16* Kb = K + (size_t)bh * 65536;
  const f16* Vb = VT + (size_t)bh * 65536;
  const float* pb = pos + ((size_t)h * 1024 + q) * 1024;

  f16* mK0 = &KS[wid][0][0]; f16* mK1 = &KS[wid][1][0]; f16* mK2 = &KS[wid][2][0];
  f16* mV0 = &VS[wid][0][0]; f16* mV1 = &VS[wid][1][0]; f16* mV2 = &VS[wid][2][0];

  float m_run = -1e30f, l_run = 0.f;
  f32x4 acc[4] = {};  // O^T: acc[df][r] -> d = df*16 + grp*4 + r, col q
  f32x4 psA, psB;

  // wave-private staging: K [dc8][kv16][8], V [kc2][d64][8]; 2 insts each.
  auto stageKV = [&](f16* dk, f16* dv, int kv0) {
#pragma unroll
    for (int i = 0; i < 2; ++i) {
      int c = i * 64 + lane;
      gload16(Kb + (size_t)(kv0 + (c & 15)) * 64 + (c >> 4) * 8, dk + c * 8);
      gload16(Vb + (size_t)lane * 1024 + kv0 + i * 8, dv + c * 8);
    }
  };
  auto loadpos = [&](f32x4& ps, int kv0) {
    ps = *reinterpret_cast<const f32x4*>(pb + kv0 + grp * 4);
  };
  auto qk = [&](const f16* kb, const f32x4& ps) -> f32x4 {
    __builtin_amdgcn_s_setprio(1);
    f16x8 kf0 = *reinterpret_cast<const f16x8*>(kb + (grp * 16 + cq) * 8);
    f16x8 kf1 = *reinterpret_cast<const f16x8*>(kb + ((4 + grp) * 16 + cq) * 8);
    f32x4 z = {0.f, 0.f, 0.f, 0.f};
    z = __builtin_amdgcn_mfma_f32_16x16x32_f16(kf0, qf0, z, 0, 0, 0);
    z = __builtin_amdgcn_mfma_f32_16x16x32_f16(kf1, qf1, z, 0, 0, 0);
    __builtin_amdgcn_s_setprio(0);
    return z + ps;
  };
  auto smpv = [&](const f16* vb, const f32x4& st) {
    float tm = fmaxf(fmaxf(st[0], st[1]), fmaxf(st[2], st[3]));
    tm = fmaxf(tm, __shfl_xor(tm, 16));
    tm = fmaxf(tm, __shfl_xor(tm, 32));
    if (!__all(tm <= m_run + 8.f)) {  // T13 defer-rescale
      const float m_new = fmaxf(m_run, tm);
      const float corr = __expf(m_run - m_new);
      l_run *= corr;
#pragma unroll
      for (int df = 0; df < 4; ++df) acc[df] *= corr;
      m_run = m_new;
    }
    float ls = 0.f;
    f16x4 pf;
#pragma unroll
    for (int r = 0; r < 4; ++r) {
      float p = __expf(st[r] - m_run);
      ls += p;
      pf[r] = (f16)p;
    }
    ls += __shfl_xor(ls, 16);
    ls += __shfl_xor(ls, 32);
    l_run += ls;
    __builtin_amdgcn_s_setprio(1);
#pragma unroll
    for (int df = 0; df < 4; ++df) {
      f16x4 vf = *reinterpret_cast<const f16x4*>(
          vb + ((grp >> 1) * 64 + df * 16 + cq) * 8 + (grp & 1) * 4);
      acc[df] = __builtin_amdgcn_mfma_f32_16x16x16f16(vf, pf, acc[df], 0, 0, 0);
    }
    __builtin_amdgcn_s_setprio(0);
  };

  // prologue: tiles 0,1 + pos 0,1   (issue order: g0 p0 g1 p1)
  stageKV(mK0, mV0, 0);
  loadpos(psA, 0);
  asm volatile("" ::: "memory");
  stageKV(mK1, mV1, 16);
  loadpos(psB, 16);
  asm volatile("" ::: "memory");

  // Window T (buf T%3): stage(T+2)->(T+2)%3; vmcnt(9): younger in flight =
  // g(T+1)x4 + p(T+1) + g(T+2)x4; tail T=62 -> 5, T=63 -> 0.
#define W(T, KC, VC, KN, VN, PSX, VM)                                   \
  {                                                                     \
    if ((T) + 2 < 64) stageKV(KN, VN, ((T) + 2) * 16);                  \
    asm volatile("s_waitcnt vmcnt(" #VM ")" ::: "memory");              \
    f32x4 st = qk(KC, PSX);                                             \
    if ((T) + 2 < 64) loadpos(PSX, ((T) + 2) * 16);                     \
    smpv(VC, st);                                                       \
  }

  W(0,  mK0, mV0, mK2, mV2, psA, 9) W(1,  mK1, mV1, mK0, mV0, psB, 9)
  W(2,  mK2, mV2, mK1, mV1, psA, 9) W(3,  mK0, mV0, mK2, mV2, psB, 9)
  W(4,  mK1, mV1, mK0, mV0, psA, 9) W(5,  mK2, mV2, mK1, mV1, psB, 9)
  W(6,  mK0, mV0, mK2, mV2, psA, 9) W(7,  mK1, mV1, mK0, mV0, psB, 9)
  W(8,  mK2, mV2, mK1, mV1, psA, 9) W(9,  mK0, mV0, mK2, mV2, psB, 9)
  W(10, mK1, mV1, mK0, mV0, psA, 9) W(11, mK2, mV2, mK1, mV1, psB, 9)
  W(12, mK0, mV0, mK2, mV2, psA, 9) W(13, mK1, mV1, mK0, mV0, psB, 9)
  W(14, mK2, mV2, mK1, mV1, psA, 9) W(15, mK0, mV0, mK2, mV2, psB, 9)
  W(16, mK1, mV1, mK0, mV0, psA, 9) W(17, mK2, mV2, mK1, mV1, psB, 9)
  W(18, mK0, mV0, mK2, mV2, psA, 9) W(19, mK1, mV1, mK0, mV0, psB, 9)
  W(20, mK2, mV2, mK1, mV1, psA, 9) W(21, mK0, mV0, mK2, mV2, psB, 9)
  W(22, mK1, mV1, mK0, mV0, psA, 9) W(23, mK2, mV2, mK1, mV1, psB, 9)
  W(24, mK0, mV0, mK2, mV2, psA, 9) W(25, mK1, mV1, mK0, mV0, psB, 9)
  W(26, mK2, mV2, mK1, mV1, psA, 9) W(27, mK0, mV0, mK2, mV2, psB, 9)
  W(28, mK1, mV1, mK0, mV0, psA, 9) W(29, mK2, mV2, mK1, mV1, psB, 9)
  W(30, mK0, mV0, mK2, mV2, psA, 9) W(31, mK1, mV1, mK0, mV0, psB, 9)
  W(32, mK2, mV2, mK1, mV1, psA, 9) W(33, mK0, mV0, mK2, mV2, psB, 9)
  W(34, mK1, mV1, mK0, mV0, psA, 9) W(35, mK2, mV2, mK1, mV1, psB, 9)
  W(36, mK0, mV0, mK2, mV2, psA, 9) W(37, mK1, mV1, mK0, mV0, psB, 9)
  W(38, mK2, mV2, mK1, mV1, psA, 9) W(39, mK0, mV0, mK2, mV2, psB, 9)
  W(40, mK1, mV1, mK0, mV0, psA, 9) W(41, mK2, mV2, mK1, mV1, psB, 9)
  W(42, mK0, mV0, mK2, mV2, psA, 9) W(43, mK1, mV1, mK0, mV0, psB, 9)
  W(44, mK2, mV2, mK1, mV1, psA, 9) W(45, mK0, mV0, mK2, mV2, psB, 9)
  W(46, mK1, mV1, mK0, mV0, psA, 9) W(47, mK2, mV2, mK1, mV1, psB, 9)
  W(48, mK0, mV0, mK2, mV2, psA, 9) W(49, mK1, mV1, mK0, mV0, psB, 9)
  W(50, mK2, mV2, mK1, mV1, psA, 9) W(51, mK0, mV0, mK2, mV2, psB, 9)
  W(52, mK1, mV1, mK0, mV0, psA, 9) W(53, mK2, mV2, mK1, mV1, psB, 9)
  W(54, mK0, mV0, mK2, mV2, psA, 9) W(55, mK1, mV1, mK0, mV0, psB, 9)
  W(56, mK2, mV2, mK1, mV1, psA, 9) W(57, mK0, mV0, mK2, mV2, psB, 9)
  W(58, mK1, mV1, mK0, mV0, psA, 9) W(59, mK2, mV2, mK1, mV1, psB, 9)
  W(60, mK0, mV0, mK2, mV2, psA, 9) W(61, mK1, mV1, mK0, mV0, psB, 9)
  W(62, mK2, mV2, mK1, mV1, psA, 5) W(63, mK0, mV0, mK2, mV2, psB, 0)
#undef W

  const float sc = mask[b * 1024 + q] / l_run;
  f16* ob = attO + ((size_t)b * 1024 + q) * 768 + h * 64;
#pragma unroll
  for (int df = 0; df < 4; ++df) {
    f16x4 o;
#pragma unroll
    for (int r = 0; r < 4; ++r) o[r] = (f16)(acc[df][r] * sc);
    *reinterpret_cast<f16x4*>(ob + df * 16 + grp * 4) = o;
  }
}

extern "C" void kernel_launch(void* const* d_in, const int* in_sizes, int n_in,
                              void* d_out, int out_size, void* d_ws, size_t ws_size,
                              hipStream_t stream) {
  const float* Xq   = (const float*)d_in[0];
  const float* Xkv  = (const float*)d_in[1];
  const float* mask = (const float*)d_in[2];
  const float* Wq   = (const float*)d_in[3];
  const float* bq   = (const float*)d_in[4];
  const float* Wkv  = (const float*)d_in[5];
  const float* bkv  = (const float*)d_in[6];
  const float* Wp   = (const float*)d_in[7];
  const float* bp   = (const float*)d_in[8];
  const float* pos  = (const float*)d_in[9];
  float* out = (float*)d_out;
  char* ws = (char*)d_ws;
  if (ws_size < 42467328) return;  // need ~42.5 MB scratch

  f16* Xq_h  = (f16*)(ws + 0);         // 4096*768
  f16* Xkv_h = (f16*)(ws + 6291456);   // 4096*768
  f16* WqT   = (f16*)(ws + 12582912);  // 768*768
  f16* WkvT  = (f16*)(ws + 13762560);  // 1536*768
  f16* WpT   = (f16*)(ws + 16121856);  // 768*768
  f16* Qb    = (f16*)(ws + 17301504);  // (B,NH,LQ,HD)
  f16* Kb    = (f16*)(ws + 23592960);  // (B,NH,LKV,HD)
  f16* VTb   = (f16*)(ws + 29884416);  // (B,NH,HD,LKV)
  f16* attO  = (f16*)(ws + 36175872);  // (B,LQ,EMBED)

  prep_kernel<<<7296, 256, 0, stream>>>(Xq, Xkv, Wq, Wkv, Wp, Xq_h, Xkv_h, WqT,
                                        WkvT, WpT);
  gemm_qkv_kernel<<<576, 256, 0, stream>>>(Xq_h, WqT, bq, Qb, Xkv_h, WkvT, bkv,
                                           Kb, VTb);
  attn_kernel<<<768, 256, 0, stream>>>(Qb, Kb, VTb, pos, mask, attO);
  gemm_out_kernel<<<192, 256, 0, stream>>>(attO, WpT, bp, out);
}

// Round 12
// 129.072 us; speedup vs baseline: 1.5355x; 1.5355x over previous
//
#include <hip/hip_runtime.h>
#include <hip/hip_fp16.h>
#include <stdint.h>

// MaskCrossAttention: B=4, LQ=LKV=1024, C=EMBED=768, NH=12, HD=64, SCALE=0.125
// Round 11: r8 (all-coalesced staging; line-traffic = useful bytes) + V-read
// bank-conflict fix: V chunk XOR-swizzled (source (t&3)^(d&3) within the same
// 64B line -> coalescing preserved; read at c^(d&3) -> 2-way pairs = free).
// r8's 22M-cycle 8-way V conflict was masking the coalescing win.

typedef _Float16 f16;
typedef __attribute__((ext_vector_type(8))) _Float16 f16x8;
typedef __attribute__((ext_vector_type(4))) _Float16 f16x4;
typedef __attribute__((ext_vector_type(4))) float f32x4;

__device__ __forceinline__ void gload16(const void* g, void* l) {
  __builtin_amdgcn_global_load_lds(
      (__attribute__((address_space(1))) void*)(uintptr_t)g,
      (__attribute__((address_space(3))) void*)(uint32_t)(uintptr_t)l,
      16, 0, 0);
}

// ---------------- fused prep: cvt Xq, cvt Xkv, transpose Wq/Wkv/Wp ----------
__device__ __forceinline__ void cvt4_job(const float* __restrict__ in,
                                         f16* __restrict__ out, int i) {
  float4 v = reinterpret_cast<const float4*>(in)[i];
  f16x4 o = {(f16)v.x, (f16)v.y, (f16)v.z, (f16)v.w};
  reinterpret_cast<f16x4*>(out)[i] = o;
}
__device__ __forceinline__ void transw_job(const float* __restrict__ W,
                                           f16* __restrict__ Wt, int N, int bid,
                                           int tid) {
  int kcb = bid % 96;  // 96 = 768/8
  int n = (bid / 96) * 256 + tid;
  int k0 = kcb * 8;
  f16x8 o;
#pragma unroll
  for (int j = 0; j < 8; ++j) o[j] = (f16)W[(size_t)(k0 + j) * N + n];
  *reinterpret_cast<f16x8*>(Wt + (size_t)n * 768 + k0) = o;
}
__global__ __launch_bounds__(256) void prep_kernel(
    const float* __restrict__ Xq, const float* __restrict__ Xkv,
    const float* __restrict__ Wq, const float* __restrict__ Wkv,
    const float* __restrict__ Wp, f16* __restrict__ Xq_h,
    f16* __restrict__ Xkv_h, f16* __restrict__ WqT, f16* __restrict__ WkvT,
    f16* __restrict__ WpT) {
  const int bid = blockIdx.x, tid = threadIdx.x;
  if (bid < 3072) cvt4_job(Xq, Xq_h, bid * 256 + tid);
  else if (bid < 6144) cvt4_job(Xkv, Xkv_h, (bid - 3072) * 256 + tid);
  else if (bid < 6432) transw_job(Wq, WqT, 768, bid - 6144, tid);
  else if (bid < 7008) transw_job(Wkv, WkvT, 1536, bid - 6432, tid);
  else transw_job(Wp, WpT, 768, bid - 7008, tid);
}

// ---------------- GEMM body: C = A(4096x768) * Bt(N x 768)^T + bias ---------
template <int NDIM, int EPI>
__device__ __forceinline__ void gemm_body(int bid, f16* As, f16* Bs,
                                          const f16* __restrict__ A,
                                          const f16* __restrict__ Bt,
                                          const float* __restrict__ bias,
                                          void* __restrict__ out0,
                                          void* __restrict__ out1) {
  constexpr int KD = 768;
  const int t = threadIdx.x;
  const int lane = t & 63, wid = t >> 6;
  const int bm = bid / (NDIM / 128), bn = bid % (NDIM / 128);
  const int m0 = bm * 128, n0 = bn * 128;
  const int wm = wid >> 1, wn = wid & 1;
  const int cr = lane & 15, grp = lane >> 4;
  f32x4 acc[4][4] = {};
  for (int k0 = 0; k0 < KD; k0 += 32) {
    __syncthreads();
#pragma unroll
    for (int it = 0; it < 2; ++it) {
      int ia = it * 256 + wid * 64 + lane;
      int kc = ia >> 7, row = ia & 127;
      gload16(A + (size_t)(m0 + row) * KD + k0 + kc * 8,
              As + (it * 256 + wid * 64) * 8);
      gload16(Bt + (size_t)(n0 + row) * KD + k0 + kc * 8,
              Bs + (it * 256 + wid * 64) * 8);
    }
    __syncthreads();
    f16x8 af[4], bf[4];
#pragma unroll
    for (int mf = 0; mf < 4; ++mf)
      af[mf] = *reinterpret_cast<const f16x8*>(As + (grp * 128 + wm * 64 + mf * 16 + cr) * 8);
#pragma unroll
    for (int nf = 0; nf < 4; ++nf)
      bf[nf] = *reinterpret_cast<const f16x8*>(Bs + (grp * 128 + wn * 64 + nf * 16 + cr) * 8);
#pragma unroll
    for (int mf = 0; mf < 4; ++mf)
#pragma unroll
      for (int nf = 0; nf < 4; ++nf)
        acc[mf][nf] = __builtin_amdgcn_mfma_f32_16x16x32_f16(af[mf], bf[nf], acc[mf][nf], 0, 0, 0);
  }
#pragma unroll
  for (int mf = 0; mf < 4; ++mf) {
    int m = m0 + wm * 64 + mf * 16 + grp * 4;  // +r per reg
    int b = m >> 10, lrow = m & 1023;
#pragma unroll
    for (int nf = 0; nf < 4; ++nf) {
      int n = n0 + wn * 64 + nf * 16 + cr;
      float bv = bias[n];
      f32x4 v = acc[mf][nf];
      if constexpr (EPI == 0) {
        int h = n >> 6, d = n & 63;
        f16* dst = (f16*)out0 + (((size_t)b * 12 + h) * 1024 + lrow) * 64 + d;
#pragma unroll
        for (int r = 0; r < 4; ++r) dst[(size_t)r * 64] = (f16)((v[r] + bv) * 0.125f);
      } else if constexpr (EPI == 1) {
        if (n < 768) {
          int h = n >> 6, d = n & 63;
          f16* dst = (f16*)out0 + (((size_t)b * 12 + h) * 1024 + lrow) * 64 + d;
#pragma unroll
          for (int r = 0; r < 4; ++r) dst[(size_t)r * 64] = (f16)(v[r] + bv);
        } else {
          int n2 = n - 768;
          int h = n2 >> 6, d = n2 & 63;
          f16x4 o;
#pragma unroll
          for (int r = 0; r < 4; ++r) o[r] = (f16)(v[r] + bv);
          *reinterpret_cast<f16x4*>((f16*)out1 + (((size_t)b * 12 + h) * 64 + d) * 1024 + lrow) = o;
        }
      } else {
        float* dst = (float*)out0 + (size_t)m * 768 + n;
#pragma unroll
        for (int r = 0; r < 4; ++r) dst[(size_t)r * 768] = v[r] + bv;
      }
    }
  }
}

__global__ __launch_bounds__(256) void gemm_qkv_kernel(
    const f16* __restrict__ Xq_h, const f16* __restrict__ WqT,
    const float* __restrict__ bq, f16* __restrict__ Qb,
    const f16* __restrict__ Xkv_h, const f16* __restrict__ WkvT,
    const float* __restrict__ bkv, f16* __restrict__ Kb, f16* __restrict__ VTb) {
  __shared__ f16 As[4096];
  __shared__ f16 Bs[4096];
  const int swz = (blockIdx.x % 8) * 72 + blockIdx.x / 8;  // 576 = 8*72
  if (swz < 192)
    gemm_body<768, 0>(swz, As, Bs, Xq_h, WqT, bq, Qb, nullptr);
  else
    gemm_body<1536, 1>(swz - 192, As, Bs, Xkv_h, WkvT, bkv, Kb, VTb);
}

__global__ __launch_bounds__(256) void gemm_out_kernel(
    const f16* __restrict__ attO, const f16* __restrict__ WpT,
    const float* __restrict__ bp, float* __restrict__ out) {
  __shared__ f16 As[4096];
  __shared__ f16 Bs[4096];
  const int swz = (blockIdx.x % 8) * 24 + blockIdx.x / 8;  // 192 = 8*24
  gemm_body<768, 2>(swz, As, Bs, attO, WpT, bp, out, nullptr);
}

// ---------------- fused flash attention: coalesced + conflict-free ---------
// 768 blocks x 256 threads (4 waves x 16 q-rows), KVBLK=32, 32 tiles,
// double-buffered named LDS (A/B), 4 gload_lds/thread/tile, vmcnt(4).
// LDS layouts (rule #21: linear dest + inverse-swizzled source + swz read):
//   K  [kv32][c8][8f16]   content c = g^(kv&7)     (4 KB)  2-way banks
//   V  [d64][p4][8f16]    content p = c^(d&3)      (4 KB)  2-way pairs (fix!)
//   pos[q64][c8][4f32]    content c = g^(qr&7)     (8 KB)  2-way banks
// Block remap: 4 batches of one (h,qtile) adjacent on one XCD (pos L2-shared).
__global__ __launch_bounds__(256, 3) void attn_kernel(
    const f16* __restrict__ Q, const f16* __restrict__ K,
    const f16* __restrict__ VT, const float* __restrict__ pos,
    const float* __restrict__ mask, f16* __restrict__ attO) {
  __shared__ f16 KsA[2048], KsB[2048];   // [kv32][c8][8 f16]
  __shared__ f16 VsA[2048], VsB[2048];   // [d64][p4][8 f16]
  __shared__ float PsA[2048], PsB[2048]; // [q64][c8][4 f32]
  const int t = threadIdx.x;
  const int lane = t & 63, wid = t >> 6;
  const int xcd = blockIdx.x & 7;
  const int j = blockIdx.x >> 3;            // 0..95
  const int gidx = xcd * 24 + (j >> 2);     // 0..191 = h*16 + qtile
  const int b = j & 3;
  const int h = gidx >> 4;
  const int qt = gidx & 15;
  const int bh = b * 12 + h;
  const int cq = lane & 15, grp = lane >> 4;
  const int q = qt * 64 + wid * 16 + cq;
  const f16* Qp = Q + ((size_t)bh * 1024 + q) * 64 + grp * 8;
  const f16x8 qf0 = *reinterpret_cast<const f16x8*>(Qp);
  const f16x8 qf1 = *reinterpret_cast<const f16x8*>(Qp + 32);
  const f16* Kb = K + (size_t)bh * 65536;
  const f16* Vb = VT + (size_t)bh * 65536;
  const float* pblk = pos + ((size_t)h * 1024 + qt * 64) * 1024;

  float m_run = -1e30f, l_run = 0.f;
  f32x4 acc[4] = {};  // O^T: acc[df][r] -> d = df*16 + grp*4 + r, col q

  // staging indices (consecutive lanes stay within the same 64B source line)
  const int skv = t >> 3, skc = (t & 7) ^ ((t >> 3) & 7);          // K
  const int svd = t >> 2, svc = (t & 3) ^ ((t >> 2) & 3);          // V (swz!)
  const int pqr0 = t >> 3, pc0 = (t & 7) ^ ((t >> 3) & 7);         // pos k=0
  const int pqr1 = (256 + t) >> 3, pc1 = (t & 7) ^ (((256 + t) >> 3) & 7);
  auto stage = [&](f16* Ksb, f16* Vsb, float* Psb, int kv0) {
    gload16(Kb + (size_t)(kv0 + skv) * 64 + skc * 8, Ksb + t * 8);
    gload16(Vb + (size_t)svd * 1024 + kv0 + svc * 8, Vsb + t * 8);
    gload16(pblk + (size_t)pqr0 * 1024 + kv0 + pc0 * 4, Psb + t * 4);
    gload16(pblk + (size_t)pqr1 * 1024 + kv0 + pc1 * 4, Psb + (256 + t) * 4);
  };

  const int swc = cq & 7;  // K/pos read swizzle key
  auto compute = [&](const f16* Ksb, const f16* Vsb, const float* Psb) {
    f32x4 st[2];
    __builtin_amdgcn_s_setprio(1);
#pragma unroll
    for (int f = 0; f < 2; ++f) {
      f16x8 kf0 = *reinterpret_cast<const f16x8*>(
          Ksb + ((f * 16 + cq) * 8 + (grp ^ swc)) * 8);
      f16x8 kf1 = *reinterpret_cast<const f16x8*>(
          Ksb + ((f * 16 + cq) * 8 + ((4 + grp) ^ swc)) * 8);
      f32x4 z = {0.f, 0.f, 0.f, 0.f};
      z = __builtin_amdgcn_mfma_f32_16x16x32_f16(kf0, qf0, z, 0, 0, 0);
      z = __builtin_amdgcn_mfma_f32_16x16x32_f16(kf1, qf1, z, 0, 0, 0);
      st[f] = z + *reinterpret_cast<const f32x4*>(
                      Psb + ((wid * 16 + cq) * 8 + ((f * 4 + grp) ^ swc)) * 4);
    }
    __builtin_amdgcn_s_setprio(0);
    float tm = -1e30f;
#pragma unroll
    for (int f = 0; f < 2; ++f)
#pragma unroll
      for (int r = 0; r < 4; ++r) tm = fmaxf(tm, st[f][r]);
    tm = fmaxf(tm, __shfl_xor(tm, 16));
    tm = fmaxf(tm, __shfl_xor(tm, 32));
    if (!__all(tm <= m_run + 8.f)) {  // T13 defer-rescale
      const float m_new = fmaxf(m_run, tm);
      const float corr = __expf(m_run - m_new);
      l_run *= corr;
#pragma unroll
      for (int df = 0; df < 4; ++df) acc[df] *= corr;
      m_run = m_new;
    }
    float ls = 0.f;
    f16x4 pf[2];
#pragma unroll
    for (int f = 0; f < 2; ++f)
#pragma unroll
      for (int r = 0; r < 4; ++r) {
        float p = __expf(st[f][r] - m_run);
        ls += p;
        pf[f][r] = (f16)p;
      }
    ls += __shfl_xor(ls, 16);
    ls += __shfl_xor(ls, 32);
    l_run += ls;
    __builtin_amdgcn_s_setprio(1);
#pragma unroll
    for (int f = 0; f < 2; ++f)
#pragma unroll
      for (int df = 0; df < 4; ++df) {
        const int c = f * 2 + (grp >> 1);
        f16x4 vf = *reinterpret_cast<const f16x4*>(
            Vsb + (df * 16 + cq) * 32 + (c ^ (cq & 3)) * 8 + (grp & 1) * 4);
        acc[df] = __builtin_amdgcn_mfma_f32_16x16x16f16(vf, pf[f], acc[df], 0, 0, 0);
      }
    __builtin_amdgcn_s_setprio(0);
  };

  stage(KsA, VsA, PsA, 0);
  asm volatile("" ::: "memory");
  for (int te = 0; te < 32; te += 2) {
    stage(KsB, VsB, PsB, (te + 1) * 32);
    asm volatile("" ::: "memory");
    asm volatile("s_waitcnt vmcnt(4)" ::: "memory");
    __builtin_amdgcn_s_barrier();
    compute(KsA, VsA, PsA);
    __builtin_amdgcn_s_barrier();
    if (te + 2 < 32) {
      stage(KsA, VsA, PsA, (te + 2) * 32);
      asm volatile("" ::: "memory");
      asm volatile("s_waitcnt vmcnt(4)" ::: "memory");
    } else {
      asm volatile("s_waitcnt vmcnt(0)" ::: "memory");
    }
    __builtin_amdgcn_s_barrier();
    compute(KsB, VsB, PsB);
    if (te + 2 < 32) __builtin_amdgcn_s_barrier();
  }

  const float sc = mask[b * 1024 + q] / l_run;
  f16* ob = attO + ((size_t)b * 1024 + q) * 768 + h * 64;
#pragma unroll
  for (int df = 0; df < 4; ++df) {
    f16x4 o;
#pragma unroll
    for (int r = 0; r < 4; ++r) o[r] = (f16)(acc[df][r] * sc);
    *reinterpret_cast<f16x4*>(ob + df * 16 + grp * 4) = o;
  }
}

extern "C" void kernel_launch(void* const* d_in, const int* in_sizes, int n_in,
                              void* d_out, int out_size, void* d_ws, size_t ws_size,
                              hipStream_t stream) {
  const float* Xq   = (const float*)d_in[0];
  const float* Xkv  = (const float*)d_in[1];
  const float* mask = (const float*)d_in[2];
  const float* Wq   = (const float*)d_in[3];
  const float* bq   = (const float*)d_in[4];
  const float* Wkv  = (const float*)d_in[5];
  const float* bkv  = (const float*)d_in[6];
  const float* Wp   = (const float*)d_in[7];
  const float* bp   = (const float*)d_in[8];
  const float* pos  = (const float*)d_in[9];
  float* out = (float*)d_out;
  char* ws = (char*)d_ws;
  if (ws_size < 42467328) return;  // need ~42.5 MB scratch

  f16* Xq_h  = (f16*)(ws + 0);         // 4096*768
  f16* Xkv_h = (f16*)(ws + 6291456);   // 4096*768
  f16* WqT   = (f16*)(ws + 12582912);  // 768*768
  f16* WkvT  = (f16*)(ws + 13762560);  // 1536*768
  f16* WpT   = (f16*)(ws + 16121856);  // 768*768
  f16* Qb    = (f16*)(ws + 17301504);  // (B,NH,LQ,HD)
  f16* Kb    = (f16*)(ws + 23592960);  // (B,NH,LKV,HD)
  f16* VTb   = (f16*)(ws + 29884416);  // (B,NH,HD,LKV)
  f16* attO  = (f16*)(ws + 36175872);  // (B,LQ,EMBED)

  prep_kernel<<<7296, 256, 0, stream>>>(Xq, Xkv, Wq, Wkv, Wp, Xq_h, Xkv_h, WqT,
                                        WkvT, WpT);
  gemm_qkv_kernel<<<576, 256, 0, stream>>>(Xq_h, WqT, bq, Qb, Xkv_h, WkvT, bkv,
                                           Kb, VTb);
  attn_kernel<<<768, 256, 0, stream>>>(Qb, Kb, VTb, pos, mask, attO);
  gemm_out_kernel<<<192, 256, 0, stream>>>(attO, WpT, bp, out);
}